// Round 1
// baseline (1161.806 us; speedup 1.0000x reference)
//
#include <hip/hip_runtime.h>

#define B_ 8192
#define T_ 256
#define H_ 128
#define ROWS 16
#define NTH 512

typedef __attribute__((ext_vector_type(4))) float  f32x4;
typedef __attribute__((ext_vector_type(4))) short  short4_t;
typedef __attribute__((ext_vector_type(8))) short  short8_t;

__device__ __forceinline__ short f2bf(float f) {
    unsigned u = __builtin_bit_cast(unsigned, f);
    unsigned r = (u + 0x7FFFu + ((u >> 16) & 1u)) >> 16;
    return (short)(unsigned short)r;
}
__device__ __forceinline__ float bf2f(short s) {
    unsigned u = ((unsigned)(unsigned short)s) << 16;
    return __builtin_bit_cast(float, u);
}
__device__ __forceinline__ float fast_exp(float x) {
    return __builtin_amdgcn_exp2f(x * 1.4426950408889634f);
}
__device__ __forceinline__ float sigm(float x) {
    return __builtin_amdgcn_rcpf(1.0f + fast_exp(-x));
}
__device__ __forceinline__ float tanh_f(float x) {
    return 1.0f - 2.0f * __builtin_amdgcn_rcpf(1.0f + fast_exp(2.0f * x));
}

// Each workgroup: 16 batch rows, 8 waves. Wave w owns H-columns [16w,16w+16).
// Combined K-axis for the gate GEMM: chunks 0..3 = feat (W_ih part),
// chunks 4..7 = h_hi (W_hh), chunks 8..11 = h_lo (W_hh fragments reused).
// A-fragments stored in LDS in exact MFMA fragment order:
//   element (row i, k) -> short idx = chunk*512 + (i + 16*((k&31)>>3))*8 + (k&7)
__global__ __launch_bounds__(NTH, 2) void brits_kernel(
    const float* __restrict__ x_seq, const float* __restrict__ m_seq,
    const float* __restrict__ Wc_w,  const float* __restrict__ Wc_b,
    const float* __restrict__ Wx_w,  const float* __restrict__ Wx_b,
    const float* __restrict__ W_ih,  const float* __restrict__ W_hh,
    const float* __restrict__ b_ih,  const float* __restrict__ b_hh,
    const float* __restrict__ out_w, const float* __restrict__ out_b,
    float* __restrict__ out)
{
    __shared__ short Afrag[12 * 512];          // 12 KiB: 12 chunks x 1024B
    __shared__ float pred_s[ROWS][T_];         // 16 KiB
    __shared__ float comp_s[ROWS][T_];         // 16 KiB
    __shared__ float wx_s[H_], bx_s[H_];
    __shared__ float part_c[8][ROWS], part_p[8][ROWS];
    __shared__ float xm_x[ROWS], xm_m[ROWS];

    const int tid  = threadIdx.x;
    const int lane = tid & 63;
    const int wv   = tid >> 6;          // wave id 0..7
    const int kg   = lane >> 4;         // k-group 0..3
    const int ln16 = lane & 15;
    const int rb   = kg * 4;            // acc-layout row base
    const int row1 = tid & 15;          // feat row
    const int q    = tid >> 4;          // feat quad 0..31
    const long b0  = (long)blockIdx.x * ROWS;

    const float cb = Wc_b[0];
    const float ob = out_b[0];

    // gate columns for this lane
    const int cH = wv * 16 + ln16;      // 0..127
    const int cR = cH, cZ = cH + 128, cN = cH + 256;

    const float bR  = b_ih[cR] + b_hh[cR];
    const float bZ  = b_ih[cZ] + b_hh[cZ];
    const float bNi = b_ih[cN];
    const float bNh = b_hh[cN];
    const float WmR = W_ih[cR * 129 + 128];
    const float WmZ = W_ih[cZ * 129 + 128];
    const float WmN = W_ih[cN * 129 + 128];
    const float wcc = Wc_w[cH];
    const float owc = out_w[cH];

    // ---- preload weight B-fragments into registers (held across t-loop) ----
    short8_t wr[8], wz[8], wn[8];
#pragma unroll
    for (int kc = 0; kc < 8; ++kc) {
        const float *pr, *pz, *pn;
        if (kc < 4) {
            int off = kc * 32 + kg * 8;
            pr = W_ih + cR * 129 + off;
            pz = W_ih + cZ * 129 + off;
            pn = W_ih + cN * 129 + off;
        } else {
            int off = (kc - 4) * 32 + kg * 8;
            pr = W_hh + cR * 128 + off;
            pz = W_hh + cZ * 128 + off;
            pn = W_hh + cN * 128 + off;
        }
#pragma unroll
        for (int e = 0; e < 8; ++e) {
            wr[kc][e] = f2bf(pr[e]);
            wz[kc][e] = f2bf(pz[e]);
            wn[kc][e] = f2bf(pn[e]);
        }
    }

    // ---- LDS init ----
    if (tid < H_) { wx_s[tid] = Wx_w[tid]; bx_s[tid] = Wx_b[tid]; }
    {   // zero h hi/lo fragment chunks 4..11 (short idx 2048..6143)
        short8_t z8 = {0,0,0,0,0,0,0,0};
        *(short8_t*)&Afrag[2048 + tid * 8] = z8;
    }
    if (tid < 8 * ROWS) { ((float*)part_c)[tid] = 0.0f; ((float*)part_p)[tid] = 0.0f; }
    if (tid < ROWS) {
        xm_x[tid] = x_seq[(b0 + tid) * T_];
        xm_m[tid] = m_seq[(b0 + tid) * T_];
    }
    f32x4 hreg = {0.f, 0.f, 0.f, 0.f};
    __syncthreads();

    // ---- main recurrence ----
    for (int t = 0; t < T_; ++t) {
        // phase 1: c_t (redundant per thread), comp/pred stores, feat -> A-frags
        float sc = 0.0f;
#pragma unroll
        for (int w2 = 0; w2 < 8; ++w2) sc += part_c[w2][row1];
        const float c_t = tanh_f(sc + cb);
        if (q == 0) {
            comp_s[row1][t] = c_t;
            if (t > 0) {
                float sp = 0.0f;
#pragma unroll
                for (int w2 = 0; w2 < 8; ++w2) sp += part_p[w2][row1];
                pred_s[row1][t - 1] = sp + ob;
            }
        }
        {
            const float xv = xm_x[row1], mv = xm_m[row1];
            const float xi = mv * xv + (1.0f - mv) * c_t;
            const f32x4 wx4 = *(const f32x4*)&wx_s[q * 4];
            const f32x4 bx4 = *(const f32x4*)&bx_s[q * 4];
            short4_t fr;
#pragma unroll
            for (int e = 0; e < 4; ++e) {
                float f = xi * wx4[e] + bx4[e];
                f = f > 0.0f ? f : 0.0f;
                fr[e] = f2bf(f);
            }
            const int sidx = (q >> 3) * 512 + (row1 + 16 * ((q >> 1) & 3)) * 8 + (q & 1) * 4;
            *(short4_t*)&Afrag[sidx] = fr;
        }
        __syncthreads();  // B1: feat frags + (prev) h frags visible

        // phase 2: MFMA  g = [feat, h_hi, h_lo] @ W
        float m4[4];
#pragma unroll
        for (int e = 0; e < 4; ++e) m4[e] = xm_m[rb + e];
        f32x4 aR, aZ, aNi, aNh;
#pragma unroll
        for (int e = 0; e < 4; ++e) {
            aR[e]  = bR  + m4[e] * WmR;
            aZ[e]  = bZ  + m4[e] * WmZ;
            aNi[e] = bNi + m4[e] * WmN;
            aNh[e] = bNh;
        }
#pragma unroll
        for (int kc = 0; kc < 4; ++kc) {
            short8_t a = *(const short8_t*)&Afrag[kc * 512 + lane * 8];
            aR  = __builtin_amdgcn_mfma_f32_16x16x32_bf16(a, wr[kc], aR, 0, 0, 0);
            aZ  = __builtin_amdgcn_mfma_f32_16x16x32_bf16(a, wz[kc], aZ, 0, 0, 0);
            aNi = __builtin_amdgcn_mfma_f32_16x16x32_bf16(a, wn[kc], aNi, 0, 0, 0);
        }
#pragma unroll
        for (int kc = 4; kc < 8; ++kc) {
            short8_t a = *(const short8_t*)&Afrag[kc * 512 + lane * 8];
            aR  = __builtin_amdgcn_mfma_f32_16x16x32_bf16(a, wr[kc], aR, 0, 0, 0);
            aZ  = __builtin_amdgcn_mfma_f32_16x16x32_bf16(a, wz[kc], aZ, 0, 0, 0);
            aNh = __builtin_amdgcn_mfma_f32_16x16x32_bf16(a, wn[kc], aNh, 0, 0, 0);
        }
#pragma unroll
        for (int kc = 8; kc < 12; ++kc) {
            short8_t a = *(const short8_t*)&Afrag[kc * 512 + lane * 8];
            aR  = __builtin_amdgcn_mfma_f32_16x16x32_bf16(a, wr[kc - 4], aR, 0, 0, 0);
            aZ  = __builtin_amdgcn_mfma_f32_16x16x32_bf16(a, wz[kc - 4], aZ, 0, 0, 0);
            aNh = __builtin_amdgcn_mfma_f32_16x16x32_bf16(a, wn[kc - 4], aNh, 0, 0, 0);
        }

        // phase 3: gates + h update (registers only)
        f32x4 hnew;
#pragma unroll
        for (int e = 0; e < 4; ++e) {
            float r = sigm(aR[e]);
            float z = sigm(aZ[e]);
            float n = tanh_f(aNi[e] + r * aNh[e]);
            hnew[e] = (1.0f - z) * n + z * hreg[e];
        }
        hreg = hnew;
        __syncthreads();  // B2: all MFMA A-reads done before frag overwrite

        // phase 4: write h hi/lo fragments + dot partials + x/m prefetch
        {
            const int base = (4 + (cH >> 5)) * 512 + 16 * ((cH & 31) >> 3) * 8 + (cH & 7);
#pragma unroll
            for (int e = 0; e < 4; ++e) {
                float hv = hnew[e];
                short hi = f2bf(hv);
                float lof = hv - bf2f(hi);
                short lo = f2bf(lof);
                int si = base + (rb + e) * 8;
                Afrag[si] = hi;
                Afrag[si + 4 * 512] = lo;
            }
            f32x4 pc4, pp4;
#pragma unroll
            for (int e = 0; e < 4; ++e) { pc4[e] = hnew[e] * wcc; pp4[e] = hnew[e] * owc; }
#pragma unroll
            for (int msk = 1; msk < 16; msk <<= 1) {
#pragma unroll
                for (int e = 0; e < 4; ++e) {
                    pc4[e] += __shfl_xor(pc4[e], msk);
                    pp4[e] += __shfl_xor(pp4[e], msk);
                }
            }
            if (ln16 == 0) {
#pragma unroll
                for (int e = 0; e < 4; ++e) {
                    part_c[wv][rb + e] = pc4[e];
                    part_p[wv][rb + e] = pp4[e];
                }
            }
        }
        if (tid < ROWS) {
            int tp = (t + 1 < T_) ? (t + 1) : (T_ - 1);
            xm_x[tid] = x_seq[(b0 + tid) * T_ + tp];
            xm_m[tid] = m_seq[(b0 + tid) * T_ + tp];
        }
        __syncthreads();  // B3: partials + h frags ready for next iteration
    }

    // final pred (t = 255)
    if (tid < ROWS) {
        float sp = 0.0f;
#pragma unroll
        for (int w2 = 0; w2 < 8; ++w2) sp += part_p[w2][tid];
        pred_s[tid][T_ - 1] = sp + ob;
    }
    __syncthreads();

    // coalesced output: preds at [0, B*T), comps at [B*T, 2*B*T)
#pragma unroll
    for (int i = 0; i < 2; ++i) {
        int r = tid >> 5;
        int c = (tid & 31) * 8 + i * 4;
        *(f32x4*)&out[(b0 + r) * T_ + c] = *(const f32x4*)&pred_s[r][c];
        *(f32x4*)&out[(long)B_ * T_ + (b0 + r) * T_ + c] = *(const f32x4*)&comp_s[r][c];
    }
}

extern "C" void kernel_launch(void* const* d_in, const int* in_sizes, int n_in,
                              void* d_out, int out_size, void* d_ws, size_t ws_size,
                              hipStream_t stream) {
    const float* x_seq = (const float*)d_in[0];
    const float* m_seq = (const float*)d_in[1];
    const float* Wc_w  = (const float*)d_in[2];
    const float* Wc_b  = (const float*)d_in[3];
    const float* Wx_w  = (const float*)d_in[4];
    const float* Wx_b  = (const float*)d_in[5];
    const float* W_ih  = (const float*)d_in[6];
    const float* W_hh  = (const float*)d_in[7];
    const float* b_ih  = (const float*)d_in[8];
    const float* b_hh  = (const float*)d_in[9];
    const float* out_w = (const float*)d_in[10];
    const float* out_b = (const float*)d_in[11];
    float* out = (float*)d_out;

    dim3 grid(B_ / ROWS);   // 512 workgroups of 16 rows
    dim3 block(NTH);
    brits_kernel<<<grid, block, 0, stream>>>(x_seq, m_seq, Wc_w, Wc_b, Wx_w, Wx_b,
                                             W_ih, W_hh, b_ih, b_hh, out_w, out_b, out);
}

// Round 2
// 636.209 us; speedup vs baseline: 1.8261x; 1.8261x over previous
//
#include <hip/hip_runtime.h>

#define B_ 8192
#define T_ 256
#define H_ 128
#define ROWS 32
#define NTH 512

typedef __attribute__((ext_vector_type(4))) float f32x4;
typedef __attribute__((ext_vector_type(4))) short short4_t;
typedef __attribute__((ext_vector_type(8))) short short8_t;
typedef __attribute__((ext_vector_type(8))) _Float16 half8;
typedef __attribute__((ext_vector_type(2))) _Float16 half2_t;
typedef __attribute__((ext_vector_type(4))) unsigned int uint4_t;

__device__ __forceinline__ float fast_exp(float x) {
    return __builtin_amdgcn_exp2f(x * 1.4426950408889634f);
}
__device__ __forceinline__ float sigm(float x) {
    return __builtin_amdgcn_rcpf(1.0f + fast_exp(-x));
}
__device__ __forceinline__ float tanh_f(float x) {
    return 1.0f - 2.0f * __builtin_amdgcn_rcpf(1.0f + fast_exp(2.0f * x));
}
__device__ __forceinline__ short h16bits(float v) {
    return __builtin_bit_cast(short, (_Float16)v);
}
__device__ __forceinline__ float h16f(short s) {
    return (float)__builtin_bit_cast(_Float16, s);
}
// sum over each 16-lane group via DPP row_shr; result valid in lane (16g+15)
__device__ __forceinline__ float red16(float v) {
    v += __builtin_bit_cast(float, __builtin_amdgcn_update_dpp(0, __builtin_bit_cast(int, v), 0x111, 0xf, 0xf, true));
    v += __builtin_bit_cast(float, __builtin_amdgcn_update_dpp(0, __builtin_bit_cast(int, v), 0x112, 0xf, 0xf, true));
    v += __builtin_bit_cast(float, __builtin_amdgcn_update_dpp(0, __builtin_bit_cast(int, v), 0x114, 0xf, 0xf, true));
    v += __builtin_bit_cast(float, __builtin_amdgcn_update_dpp(0, __builtin_bit_cast(int, v), 0x118, 0xf, 0xf, true));
    return v;
}

// WG = 32 batch rows (2 row-tiles of 16), 8 waves, wave w owns H-cols [16w,16w+16).
// K-axis: chunks 0..3 = feat (W_ih), 4..7 = h f16 (W_hh). Gate GEMM via
// mfma_f32_16x16x32_f16, weights register-resident (24 half8 frags/wave).
// A-frag layout (f16, 16x16x32): elem (row i, k) -> chunk[ (i+16*((k&31)>>3))*8 + (k&7) ]
__global__ __launch_bounds__(NTH, 2) void brits_kernel(
    const float* __restrict__ x_seq, const float* __restrict__ m_seq,
    const float* __restrict__ Wc_w,  const float* __restrict__ Wc_b,
    const float* __restrict__ Wx_w,  const float* __restrict__ Wx_b,
    const float* __restrict__ W_ih,  const float* __restrict__ W_hh,
    const float* __restrict__ b_ih,  const float* __restrict__ b_hh,
    const float* __restrict__ out_w, const float* __restrict__ out_b,
    float* __restrict__ out)
{
    __shared__ __align__(16) short feat_s[2][4][512];     // [tile][chunk] 8 KiB
    __shared__ __align__(16) short h_s[2][2][4][512];     // [buf][tile][chunk] 16 KiB
    __shared__ __align__(16) short x_all[T_][ROWS];       // f16, transposed, 16 KiB
    __shared__ __align__(16) short m_all[T_][ROWS];       // f16 (exact 0/1), 16 KiB
    __shared__ __align__(16) short comp_sh[ROWS][264];    // f16 staged, 16.5 KiB
    __shared__ __align__(16) short pred_sh[ROWS][264];    // f16 staged, 16.5 KiB
    __shared__ __align__(16) float part_c[ROWS][8];       // c-dot partials [row][wave]
    __shared__ __align__(16) float wx_s[H_];
    __shared__ __align__(16) float bx_s[H_];
    __shared__ __align__(16) short ow_s[4][512];          // out_w as B-frags (col 0)

    const int tid  = threadIdx.x;
    const int lane = tid & 63;
    const int wv   = tid >> 6;          // wave 0..7
    const int kg   = lane >> 4;         // 16-lane group 0..3
    const int ln16 = lane & 15;
    const int rb   = kg * 4;            // C-layout row base
    const long b0  = (long)blockIdx.x * ROWS;

    // phase-A mapping: thread -> (row 0..31, k-octet 0..15)
    const int rowA = tid & 31;
    const int qA   = tid >> 5;

    const float cb = Wc_b[0];
    const float ob = out_b[0];

    const int cH = wv * 16 + ln16;
    const int cR = cH, cZ = cH + 128, cN = cH + 256;
    const float bR  = b_ih[cR] + b_hh[cR];
    const float bZ  = b_ih[cZ] + b_hh[cZ];
    const float bNi = b_ih[cN];
    const float bNh = b_hh[cN];
    const float WmR = W_ih[cR * 129 + 128];
    const float WmZ = W_ih[cZ * 129 + 128];
    const float WmN = W_ih[cN * 129 + 128];
    const float wcc = Wc_w[cH];

    // ---- weight B-fragments (f16) into registers, held across t-loop ----
    half8 wr[8], wz[8], wn[8];
#pragma unroll
    for (int kc = 0; kc < 8; ++kc) {
        const float *pr, *pz, *pn;
        if (kc < 4) {
            const int off = kc * 32 + kg * 8;
            pr = W_ih + cR * 129 + off;
            pz = W_ih + cZ * 129 + off;
            pn = W_ih + cN * 129 + off;
        } else {
            const int off = (kc - 4) * 32 + kg * 8;
            pr = W_hh + cR * 128 + off;
            pz = W_hh + cZ * 128 + off;
            pn = W_hh + cN * 128 + off;
        }
#pragma unroll
        for (int e = 0; e < 8; ++e) {
            wr[kc][e] = (_Float16)pr[e];
            wz[kc][e] = (_Float16)pz[e];
            wn[kc][e] = (_Float16)pn[e];
        }
    }

    // ---- one-time LDS init ----
    {   // preload full x/m panel (coalesced read, transposed f16 store)
        const int prow = tid >> 4;
        const int ptb  = (tid & 15) * 16;
        const float* xp = x_seq + (b0 + prow) * T_ + ptb;
        const float* mp = m_seq + (b0 + prow) * T_ + ptb;
#pragma unroll
        for (int i = 0; i < 4; ++i) {
            f32x4 xv = *(const f32x4*)(xp + 4 * i);
            f32x4 mv = *(const f32x4*)(mp + 4 * i);
#pragma unroll
            for (int j = 0; j < 4; ++j) {
                x_all[ptb + 4 * i + j][prow] = h16bits(xv[j]);
                m_all[ptb + 4 * i + j][prow] = h16bits(mv[j]);
            }
        }
    }
    if (tid < H_) { wx_s[tid] = Wx_w[tid]; bx_s[tid] = Wx_b[tid]; }
    {   // zero h_s[0] (h_0 = 0): 4096 shorts
        short8_t z8 = {0, 0, 0, 0, 0, 0, 0, 0};
        *(short8_t*)((short*)h_s + tid * 8) = z8;
    }
    if (tid < 256) ((float*)part_c)[tid] = 0.0f;
#pragma unroll
    for (int i = 0; i < 4; ++i) {   // out_w as B-frag, col 0 only
        const int idx = tid * 4 + i;
        const int c = idx >> 9, rl = idx & 511;
        const int ln = rl >> 3, j = rl & 7;
        const int col = ln & 15;
        const int k = 32 * c + (ln >> 4) * 8 + j;
        ((short*)ow_s)[idx] = (col == 0) ? h16bits(out_w[k]) : (short)0;
    }

    f32x4 h0reg = {0.f, 0.f, 0.f, 0.f};
    f32x4 h1reg = {0.f, 0.f, 0.f, 0.f};
    __syncthreads();

    // ---- main recurrence: 2 barriers/step, zero global traffic ----
    for (int t = 0; t < T_; ++t) {
        const int pb = t & 1, nb = pb ^ 1;

        // phase A: finalize c_t, build feat A-frags
        f32x4 p0 = *(const f32x4*)&part_c[rowA][0];
        f32x4 p1 = *(const f32x4*)&part_c[rowA][4];
        const float sc = ((p0[0] + p0[1]) + (p0[2] + p0[3])) +
                         ((p1[0] + p1[1]) + (p1[2] + p1[3]));
        const float c_t = tanh_f(sc + cb);
        const float xv = h16f(x_all[t][rowA]);
        const float mv = h16f(m_all[t][rowA]);
        const float xi = (mv != 0.0f) ? xv : c_t;
        if (qA == 0) comp_sh[rowA][t] = h16bits(c_t);
        {
            f32x4 wxa = *(const f32x4*)&wx_s[qA * 8];
            f32x4 wxb = *(const f32x4*)&wx_s[qA * 8 + 4];
            f32x4 bxa = *(const f32x4*)&bx_s[qA * 8];
            f32x4 bxb = *(const f32x4*)&bx_s[qA * 8 + 4];
            f32x4 fa, fb;
#pragma unroll
            for (int j = 0; j < 4; ++j) {
                fa[j] = fmaxf(xi * wxa[j] + bxa[j], 0.0f);
                fb[j] = fmaxf(xi * wxb[j] + bxb[j], 0.0f);
            }
            uint4_t pk;
            pk[0] = __builtin_bit_cast(unsigned int, __builtin_amdgcn_cvt_pkrtz(fa[0], fa[1]));
            pk[1] = __builtin_bit_cast(unsigned int, __builtin_amdgcn_cvt_pkrtz(fa[2], fa[3]));
            pk[2] = __builtin_bit_cast(unsigned int, __builtin_amdgcn_cvt_pkrtz(fb[0], fb[1]));
            pk[3] = __builtin_bit_cast(unsigned int, __builtin_amdgcn_cvt_pkrtz(fb[2], fb[3]));
            *(uint4_t*)&feat_s[rowA >> 4][qA >> 2][((rowA & 15) + 16 * (qA & 3)) * 8] = pk;
        }

        // hoisted acc init (m_all is read-only; legal before B1)
        short4_t m4a = *(const short4_t*)&m_all[t][rb];
        short4_t m4b = *(const short4_t*)&m_all[t][16 + rb];
        f32x4 aR0, aZ0, aNi0, aNh0, aR1, aZ1, aNi1, aNh1;
#pragma unroll
        for (int e = 0; e < 4; ++e) {
            const float m0 = h16f(m4a[e]), m1 = h16f(m4b[e]);
            aR0[e]  = bR  + m0 * WmR;  aR1[e]  = bR  + m1 * WmR;
            aZ0[e]  = bZ  + m0 * WmZ;  aZ1[e]  = bZ  + m1 * WmZ;
            aNi0[e] = bNi + m0 * WmN;  aNi1[e] = bNi + m1 * WmN;
            aNh0[e] = bNh;             aNh1[e] = bNh;
        }
        f32x4 pacc = {0.f, 0.f, 0.f, 0.f};
        __syncthreads();  // B1: feat frags visible

        // feat chunks
#pragma unroll
        for (int kc = 0; kc < 4; ++kc) {
            half8 a0 = __builtin_bit_cast(half8, *(const short8_t*)&feat_s[0][kc][lane * 8]);
            half8 a1 = __builtin_bit_cast(half8, *(const short8_t*)&feat_s[1][kc][lane * 8]);
            aR0  = __builtin_amdgcn_mfma_f32_16x16x32_f16(a0, wr[kc], aR0, 0, 0, 0);
            aZ0  = __builtin_amdgcn_mfma_f32_16x16x32_f16(a0, wz[kc], aZ0, 0, 0, 0);
            aNi0 = __builtin_amdgcn_mfma_f32_16x16x32_f16(a0, wn[kc], aNi0, 0, 0, 0);
            aR1  = __builtin_amdgcn_mfma_f32_16x16x32_f16(a1, wr[kc], aR1, 0, 0, 0);
            aZ1  = __builtin_amdgcn_mfma_f32_16x16x32_f16(a1, wz[kc], aZ1, 0, 0, 0);
            aNi1 = __builtin_amdgcn_mfma_f32_16x16x32_f16(a1, wn[kc], aNi1, 0, 0, 0);
        }
        // h chunks (+ lagged pred misc on waves 4/5)
#pragma unroll
        for (int kc = 0; kc < 4; ++kc) {
            half8 a0 = __builtin_bit_cast(half8, *(const short8_t*)&h_s[pb][0][kc][lane * 8]);
            half8 a1 = __builtin_bit_cast(half8, *(const short8_t*)&h_s[pb][1][kc][lane * 8]);
            aR0  = __builtin_amdgcn_mfma_f32_16x16x32_f16(a0, wr[4 + kc], aR0, 0, 0, 0);
            aZ0  = __builtin_amdgcn_mfma_f32_16x16x32_f16(a0, wz[4 + kc], aZ0, 0, 0, 0);
            aNh0 = __builtin_amdgcn_mfma_f32_16x16x32_f16(a0, wn[4 + kc], aNh0, 0, 0, 0);
            aR1  = __builtin_amdgcn_mfma_f32_16x16x32_f16(a1, wr[4 + kc], aR1, 0, 0, 0);
            aZ1  = __builtin_amdgcn_mfma_f32_16x16x32_f16(a1, wz[4 + kc], aZ1, 0, 0, 0);
            aNh1 = __builtin_amdgcn_mfma_f32_16x16x32_f16(a1, wn[4 + kc], aNh1, 0, 0, 0);
            if (wv == 4) {
                half8 bfr = __builtin_bit_cast(half8, *(const short8_t*)&ow_s[kc][lane * 8]);
                pacc = __builtin_amdgcn_mfma_f32_16x16x32_f16(a0, bfr, pacc, 0, 0, 0);
            }
            if (wv == 5) {
                half8 bfr = __builtin_bit_cast(half8, *(const short8_t*)&ow_s[kc][lane * 8]);
                pacc = __builtin_amdgcn_mfma_f32_16x16x32_f16(a1, bfr, pacc, 0, 0, 0);
            }
        }

        // gates + h update (f32 carry in registers)
        f32x4 hn0, hn1;
#pragma unroll
        for (int e = 0; e < 4; ++e) {
            const float r0 = sigm(aR0[e]), z0 = sigm(aZ0[e]);
            const float n0 = tanh_f(aNi0[e] + r0 * aNh0[e]);
            hn0[e] = z0 * (h0reg[e] - n0) + n0;
            const float r1 = sigm(aR1[e]), z1 = sigm(aZ1[e]);
            const float n1 = tanh_f(aNi1[e] + r1 * aNh1[e]);
            hn1[e] = z1 * (h1reg[e] - n1) + n1;
        }
        h0reg = hn0; h1reg = hn1;

        // write h frags (f16) into next buffer
        const int hc = cH >> 5;
        const int hbase = ((cH & 31) >> 3) * 128 + (cH & 7);
#pragma unroll
        for (int e = 0; e < 4; ++e) {
            h_s[nb][0][hc][hbase + (rb + e) * 8] = h16bits(hn0[e]);
            h_s[nb][1][hc][hbase + (rb + e) * 8] = h16bits(hn1[e]);
        }
        // c-dot partials: exact f32, DPP reduce over 16 cols
#pragma unroll
        for (int e = 0; e < 4; ++e) {
            const float s0 = red16(hn0[e] * wcc);
            const float s1 = red16(hn1[e] * wcc);
            if (ln16 == 15) {
                part_c[rb + e][wv]      = s0;
                part_c[16 + rb + e][wv] = s1;
            }
        }
        // lagged pred write: pacc = h_t . out_w  ->  preds[t-1]
        if ((wv == 4 || wv == 5) && ln16 == 0 && t > 0) {
#pragma unroll
            for (int e = 0; e < 4; ++e)
                pred_sh[(wv - 4) * 16 + rb + e][t - 1] = h16bits(pacc[e] + ob);
        }
        __syncthreads();  // B2
    }

    // final pred from h_T (in buffer 0 after t=255)
    if (wv == 4 || wv == 5) {
        f32x4 pacc = {0.f, 0.f, 0.f, 0.f};
#pragma unroll
        for (int kc = 0; kc < 4; ++kc) {
            half8 a = __builtin_bit_cast(half8, *(const short8_t*)&h_s[0][wv - 4][kc][lane * 8]);
            half8 bfr = __builtin_bit_cast(half8, *(const short8_t*)&ow_s[kc][lane * 8]);
            pacc = __builtin_amdgcn_mfma_f32_16x16x32_f16(a, bfr, pacc, 0, 0, 0);
        }
        if (ln16 == 0) {
#pragma unroll
            for (int e = 0; e < 4; ++e)
                pred_sh[(wv - 4) * 16 + rb + e][T_ - 1] = h16bits(pacc[e] + ob);
        }
    }
    __syncthreads();

    // coalesced output: preds [0, B*T), comps [B*T, 2*B*T)
    {
        const int orow = tid >> 4;
        const int oc   = (tid & 15) * 16;
        short8_t r0 = *(const short8_t*)&pred_sh[orow][oc];
        short8_t r1 = *(const short8_t*)&pred_sh[orow][oc + 8];
        float* gp = out + (b0 + orow) * T_ + oc;
#pragma unroll
        for (int i = 0; i < 4; ++i) {
            f32x4 o;
            o[0] = h16f((i < 2) ? r0[i * 4 + 0] : r1[(i - 2) * 4 + 0]);
            o[1] = h16f((i < 2) ? r0[i * 4 + 1] : r1[(i - 2) * 4 + 1]);
            o[2] = h16f((i < 2) ? r0[i * 4 + 2] : r1[(i - 2) * 4 + 2]);
            o[3] = h16f((i < 2) ? r0[i * 4 + 3] : r1[(i - 2) * 4 + 3]);
            *(f32x4*)(gp + 4 * i) = o;
        }
        short8_t c0v = *(const short8_t*)&comp_sh[orow][oc];
        short8_t c1v = *(const short8_t*)&comp_sh[orow][oc + 8];
        float* gc = out + (long)B_ * T_ + (b0 + orow) * T_ + oc;
#pragma unroll
        for (int i = 0; i < 4; ++i) {
            f32x4 o;
            o[0] = h16f((i < 2) ? c0v[i * 4 + 0] : c1v[(i - 2) * 4 + 0]);
            o[1] = h16f((i < 2) ? c0v[i * 4 + 1] : c1v[(i - 2) * 4 + 1]);
            o[2] = h16f((i < 2) ? c0v[i * 4 + 2] : c1v[(i - 2) * 4 + 2]);
            o[3] = h16f((i < 2) ? c0v[i * 4 + 3] : c1v[(i - 2) * 4 + 3]);
            *(f32x4*)(gc + 4 * i) = o;
        }
    }
}

extern "C" void kernel_launch(void* const* d_in, const int* in_sizes, int n_in,
                              void* d_out, int out_size, void* d_ws, size_t ws_size,
                              hipStream_t stream) {
    const float* x_seq = (const float*)d_in[0];
    const float* m_seq = (const float*)d_in[1];
    const float* Wc_w  = (const float*)d_in[2];
    const float* Wc_b  = (const float*)d_in[3];
    const float* Wx_w  = (const float*)d_in[4];
    const float* Wx_b  = (const float*)d_in[5];
    const float* W_ih  = (const float*)d_in[6];
    const float* W_hh  = (const float*)d_in[7];
    const float* b_ih  = (const float*)d_in[8];
    const float* b_hh  = (const float*)d_in[9];
    const float* out_w = (const float*)d_in[10];
    const float* out_b = (const float*)d_in[11];
    float* out = (float*)d_out;

    dim3 grid(B_ / ROWS);   // 256 workgroups = 1 per CU, single round
    dim3 block(NTH);
    brits_kernel<<<grid, block, 0, stream>>>(x_seq, m_seq, Wc_w, Wc_b, Wx_w, Wx_b,
                                             W_ih, W_hh, b_ih, b_hh, out_w, out_b, out);
}